// Round 6
// baseline (220.433 us; speedup 1.0000x reference)
//
#include <hip/hip_runtime.h>
#include <hip/hip_bf16.h>
#include <cstdint>

typedef __bf16 bf16x8 __attribute__((ext_vector_type(8)));
typedef __bf16 bf16x4 __attribute__((ext_vector_type(4)));
typedef float  f32x4  __attribute__((ext_vector_type(4)));

__device__ __forceinline__ int div25(int v) { return (v * 1311) >> 15; }  // exact for v <= 1310

#if __has_builtin(__builtin_amdgcn_exp2f)
__device__ __forceinline__ float fast_exp2(float x) { return __builtin_amdgcn_exp2f(x); }
#else
__device__ __forceinline__ float fast_exp2(float x) { return exp2f(x); }
#endif

// ---- dtype sniff (parallel): flag=1 if x is bf16, 0 if fp32 ----
__global__ void k_sniff(const unsigned short* __restrict__ x, int* __restrict__ flag)
{
    int lane = threadIdx.x & 63;
    unsigned short h = x[2 * lane];
    int e = (h >> 7) & 0xFF;
    unsigned long long m = __ballot(e >= 90 && e <= 143);
    if (lane == 0) *flag = (__popcll(m) > 32) ? 1 : 0;
}

// ---- transpose + convert x to bf16: (b,256,625) -> xT (b,640,256), pad rows zeroed ----
__global__ void k_transcvt(const void* __restrict__ src, __bf16* __restrict__ dst,
                           const int* __restrict__ flag,
                           int R, int C, int Cpad, int src_bstride, int dst_bstride)
{
    __shared__ float tile[64][65];
    int isbf = *flag;
    int b  = blockIdx.z;
    int r0 = blockIdx.y * 64, c0 = blockIdx.x * 64;
    int tc = threadIdx.x & 63, tg = threadIdx.x >> 6;
    const unsigned short* sb = (const unsigned short*)src + (size_t)b * src_bstride;
    const float*          sf = (const float*)src          + (size_t)b * src_bstride;
    #pragma unroll
    for (int rr = 0; rr < 16; ++rr) {
        int r = r0 + tg * 16 + rr, c = c0 + tc;
        float v = 0.f;
        if (r < R && c < C) {
            if (isbf) v = __uint_as_float((unsigned int)sb[r * C + c] << 16);
            else      v = sf[r * C + c];
        }
        tile[tg * 16 + rr][tc] = v;
    }
    __syncthreads();
    __bf16* d = dst + (size_t)b * dst_bstride;
    #pragma unroll
    for (int rr = 0; rr < 16; ++rr) {
        int c = c0 + tg * 16 + rr, r = r0 + tc;
        if (c < Cpad && r < R) d[(size_t)c * R + r] = (__bf16)tile[tc][tg * 16 + rr];
    }
}

// ---- weight prep: transpose+cvt; fold qscale*log2e into q-columns of Wt ----
__global__ void k_wprep(const void* __restrict__ Wqkv, const void* __restrict__ Wout,
                        __bf16* __restrict__ Wt, __bf16* __restrict__ WoT,
                        const int* __restrict__ flag)
{
    __shared__ float tile[64][65];
    int isbf = *flag;
    int isqkv = (blockIdx.x < 12);
    int bx = isqkv ? blockIdx.x : (blockIdx.x - 12);
    const void* src = isqkv ? Wqkv : Wout;
    __bf16* dst = isqkv ? Wt : WoT;
    int R = 256, C = isqkv ? 768 : 256;
    int r0 = blockIdx.y * 64, c0 = bx * 64;
    int tc = threadIdx.x & 63, tg = threadIdx.x >> 6;
    const unsigned short* sb = (const unsigned short*)src;
    const float*          sf = (const float*)src;
    #pragma unroll
    for (int rr = 0; rr < 16; ++rr) {
        int r = r0 + tg * 16 + rr, c = c0 + tc;
        float v;
        if (isbf) v = __uint_as_float((unsigned int)sb[r * C + c] << 16);
        else      v = sf[r * C + c];
        tile[tg * 16 + rr][tc] = v;
    }
    __syncthreads();
    const float qs = 0.25503494f;  // 32^-0.5 * log2(e)  (exp2-folded)
    #pragma unroll
    for (int rr = 0; rr < 16; ++rr) {
        int c = c0 + tg * 16 + rr, r = r0 + tc;
        float v = tile[tc][tg * 16 + rr];
        if (isqkv && c < 256) v *= qs;
        dst[(size_t)c * R + r] = (__bf16)v;
    }
}

// ---- bias table: biasT[h][i][j] bf16 (i-major, j contig), pre-multiplied by log2e.
//      cols j>=625 = -43281 (exp2 -> 0). ----
__global__ void k_bias(const void* __restrict__ rel, __bf16* __restrict__ biasT,
                       const int* __restrict__ flag)
{
    const float LOG2E = 1.4426950408889634f;
    int isbf = *flag;
    int i = blockIdx.x;
    int di = div25(i), ri = i - 25 * di;
    for (int it = 0; it < 3; ++it) {
        int j = it * 256 + threadIdx.x;
        if (j >= 640) break;
        int dj = div25(j);
        int idx = (di - dj + 24) * 49 + ri - (j - 25 * dj) + 24;
        idx = min(max(idx, 0), 2400);
        float vals[8];
        if (isbf) {
            bf16x8 r8 = *(const bf16x8*)((const __bf16*)rel + (size_t)idx * 8);
            #pragma unroll
            for (int h = 0; h < 8; ++h) vals[h] = (float)r8[h];
        } else {
            const float* rf = (const float*)rel + (size_t)idx * 8;
            #pragma unroll
            for (int h = 0; h < 8; ++h) vals[h] = rf[h];
        }
        #pragma unroll
        for (int h = 0; h < 8; ++h) {
            float v = (j >= 625) ? -43281.f : vals[h] * LOG2E;
            biasT[((size_t)h * 640 + i) * 640 + j] = (__bf16)v;
        }
    }
}

// -------- QKV projection, LDS-staged 128x128 tile, BK=32, coalesced epilogue ----------
#define AS(r, c) pool[(size_t)(r) * 40 + (c)]
#define BS(r, c) pool[5120 + (size_t)(r) * 40 + (c)]
#define CS(r, c) pool[(size_t)(r) * 44 + (c)]
__global__ __launch_bounds__(256, 2) void k_qkv(
    const __bf16* __restrict__ xT,   // (b,640,256), pad rows zeroed
    const __bf16* __restrict__ Wt,   // (768,256)
    __bf16* __restrict__ Q,          // (b,8,640,32) scaled by 32^-.5*log2e
    __bf16* __restrict__ Km,         // (b,8,640,32)
    __bf16* __restrict__ Vt)         // (b,8,32,640)
{
    __shared__ __align__(16) __bf16 pool[10240];  // As[128][40] | Bs[128][40]; Cs[128][44] reuses
    int b = blockIdx.z, pt = blockIdx.y, jt = blockIdx.x;
    int p0 = pt * 128, j0 = jt * 128;
    int tid = threadIdx.x;
    int w = tid >> 6, lane = tid & 63;
    int quad = lane >> 4, l15 = lane & 15;
    int wr = w >> 1, wc = w & 1;

    int srow = tid >> 2, scg = (tid & 3) * 8;
    const __bf16* ag  = xT + ((size_t)(b * 640 + p0 + srow) * 256) + scg;
    const __bf16* ag2 = ag + 64 * 256;
    const __bf16* bg  = Wt + ((size_t)(j0 + srow) * 256) + scg;
    const __bf16* bg2 = bg + 64 * 256;

    f32x4 acc[4][4] = {};
    for (int kk = 0; kk < 8; ++kk) {
        int c0 = kk * 32;
        bf16x8 a0 = *(const bf16x8*)(ag + c0);
        bf16x8 a1 = *(const bf16x8*)(ag2 + c0);
        bf16x8 b0 = *(const bf16x8*)(bg + c0);
        bf16x8 b1 = *(const bf16x8*)(bg2 + c0);
        __syncthreads();
        *(bf16x8*)(&AS(srow, scg))      = a0;
        *(bf16x8*)(&AS(64 + srow, scg)) = a1;
        *(bf16x8*)(&BS(srow, scg))      = b0;
        *(bf16x8*)(&BS(64 + srow, scg)) = b1;
        __syncthreads();
        bf16x8 af[4], bfr[4];
        #pragma unroll
        for (int t = 0; t < 4; ++t) {
            af[t]  = *(const bf16x8*)(&AS(wr * 64 + t * 16 + l15, quad * 8));
            bfr[t] = *(const bf16x8*)(&BS(wc * 64 + t * 16 + l15, quad * 8));
        }
        #pragma unroll
        for (int i = 0; i < 4; ++i)
            #pragma unroll
            for (int j = 0; j < 4; ++j)
                acc[i][j] = __builtin_amdgcn_mfma_f32_16x16x32_bf16(af[i], bfr[j], acc[i][j], 0, 0, 0);
    }

    if (jt < 4) {
        // q/k blocks: 4 passes; stage 128p x 32dh in Cs (stride 44: 2-way-free), b64 stores
        for (int r = 0; r < 4; ++r) {
            __syncthreads();
            if (wc == (r >> 1)) {
                #pragma unroll
                for (int i = 0; i < 4; ++i) {
                    #pragma unroll
                    for (int js = 0; js < 2; ++js) {
                        int jp = (r & 1) * 2 + js;
                        int col = js * 16 + l15;
                        int prow = wr * 64 + i * 16 + quad * 4;
                        #pragma unroll
                        for (int rr = 0; rr < 4; ++rr)
                            CS(prow + rr, col) = (__bf16)acc[i][jp][rr];
                    }
                }
            }
            __syncthreads();
            int jj = j0 + r * 32;
            __bf16* dst; int hh;
            if (jj < 256) { hh = jj >> 5; dst = Q; }
            else          { hh = (jj - 256) >> 5; dst = Km; }
            int p = tid >> 1, d0 = (tid & 1) * 16;
            size_t base = ((size_t)((b * 8 + hh) * 640) + p0 + p) * 32 + d0;
            #pragma unroll
            for (int k4 = 0; k4 < 4; ++k4) {
                bf16x4 v4 = *(const bf16x4*)(&CS(p, d0 + k4 * 4));
                *(bf16x4*)(dst + base + k4 * 4) = v4;
            }
        }
    } else {
        // v blocks: direct b64 stores (natural C layout)
        #pragma unroll
        for (int i = 0; i < 4; ++i) {
            #pragma unroll
            for (int j = 0; j < 4; ++j) {
                int jj = j0 + wc * 64 + j * 16 + l15 - 512;
                int h = jj >> 5, t = jj & 31;
                int p = p0 + wr * 64 + i * 16 + quad * 4;
                bf16x4 vv;
                #pragma unroll
                for (int rr = 0; rr < 4; ++rr) vv[rr] = (__bf16)acc[i][j][rr];
                *(bf16x4*)(Vt + ((size_t)((b * 8 + h) * 32) + t) * 640 + p) = vv;
            }
        }
    }
}

// -------- fused attention v4: XCD-local grid + 1-deep register prefetch ----------
// grid(x=bh, y=i-tile): all blocks of head h share XCD under %8 round-robin ->
// bias slice (0.8 MB) L2-resident, K/V fetched once per XCD.
__global__ __launch_bounds__(128, 4) void k_attn(
    const __bf16* __restrict__ Q,
    const __bf16* __restrict__ Km,
    const __bf16* __restrict__ Vt,
    const __bf16* __restrict__ biasT,  // (8,640,640) i-major, *log2e
    __bf16* __restrict__ ctx)          // (b,640,256), channel = h*32+dh
{
    __shared__ __align__(16) __bf16 P[2][2][32][40];
    __shared__ float ssum[2][32];
    int bh = blockIdx.x;
    int b = bh >> 3, h = bh & 7;
    int tid = threadIdx.x, w = tid >> 6, lane = tid & 63;
    int quad = lane >> 4, l15 = lane & 15;
    int i0 = (blockIdx.y * 2 + w) * 32;    // wave-private i-tile

    bf16x8 qa0 = *(const bf16x8*)(Q + ((size_t)bh * 640 + i0 + l15) * 32 + quad * 8);
    bf16x8 qa1 = *(const bf16x8*)(Q + ((size_t)bh * 640 + i0 + 16 + l15) * 32 + quad * 8);
    const __bf16* kbase = Km + (size_t)bh * 640 * 32 + quad * 8;
    const __bf16* vbase = Vt + ((size_t)bh * 32 + l15) * 640 + quad * 8;
    const __bf16* bb0 = biasT + ((size_t)h * 640 + i0 + l15) * 640 + quad * 4;
    const __bf16* bb1 = bb0 + (size_t)16 * 640;

    f32x4 o[2][2] = {};
    float psum0 = 0.f, psum1 = 0.f;

    // preload chunk 0
    bf16x8 k0 = *(const bf16x8*)(kbase + (size_t)l15 * 32);
    bf16x8 k1 = *(const bf16x8*)(kbase + (size_t)(16 + l15) * 32);
    bf16x8 v0 = *(const bf16x8*)(vbase);
    bf16x8 v1 = *(const bf16x8*)(vbase + (size_t)16 * 640);
    bf16x4 c00 = *(const bf16x4*)(bb0);
    bf16x4 c10 = *(const bf16x4*)(bb0 + 16);
    bf16x4 c01 = *(const bf16x4*)(bb1);
    bf16x4 c11 = *(const bf16x4*)(bb1 + 16);

    for (int c = 0; c < 20; ++c) {
        int jn = min(c + 1, 19) * 32;      // next chunk (clamped; last re-load is L1-hot)
        bf16x8 k0n = *(const bf16x8*)(kbase + (size_t)(jn + l15) * 32);
        bf16x8 k1n = *(const bf16x8*)(kbase + (size_t)(jn + 16 + l15) * 32);
        bf16x8 v0n = *(const bf16x8*)(vbase + jn);
        bf16x8 v1n = *(const bf16x8*)(vbase + (size_t)16 * 640 + jn);
        bf16x4 n00 = *(const bf16x4*)(bb0 + jn);
        bf16x4 n10 = *(const bf16x4*)(bb0 + jn + 16);
        bf16x4 n01 = *(const bf16x4*)(bb1 + jn);
        bf16x4 n11 = *(const bf16x4*)(bb1 + jn + 16);

        f32x4 f00, f10, f01, f11;
        #pragma unroll
        for (int rr = 0; rr < 4; ++rr) {
            f00[rr] = (float)c00[rr]; f10[rr] = (float)c10[rr];
            f01[rr] = (float)c01[rr]; f11[rr] = (float)c11[rr];
        }
        f32x4 s00 = __builtin_amdgcn_mfma_f32_16x16x32_bf16(k0, qa0, f00, 0, 0, 0);
        f32x4 s10 = __builtin_amdgcn_mfma_f32_16x16x32_bf16(k1, qa0, f10, 0, 0, 0);
        f32x4 s01 = __builtin_amdgcn_mfma_f32_16x16x32_bf16(k0, qa1, f01, 0, 0, 0);
        f32x4 s11 = __builtin_amdgcn_mfma_f32_16x16x32_bf16(k1, qa1, f11, 0, 0, 0);
        bf16x4 p00, p10, p01, p11;
        #pragma unroll
        for (int rr = 0; rr < 4; ++rr) {
            float e00 = fast_exp2(s00[rr]); psum0 += e00; p00[rr] = (__bf16)e00;
            float e10 = fast_exp2(s10[rr]); psum0 += e10; p10[rr] = (__bf16)e10;
            float e01 = fast_exp2(s01[rr]); psum1 += e01; p01[rr] = (__bf16)e01;
            float e11 = fast_exp2(s11[rr]); psum1 += e11; p11[rr] = (__bf16)e11;
        }
        int buf = c & 1;
        *(bf16x4*)(&P[w][buf][l15][quad * 4])           = p00;   // ds_write_b64
        *(bf16x4*)(&P[w][buf][l15][16 + quad * 4])      = p10;
        *(bf16x4*)(&P[w][buf][16 + l15][quad * 4])      = p01;
        *(bf16x4*)(&P[w][buf][16 + l15][16 + quad * 4]) = p11;
        bf16x8 pa0 = *(const bf16x8*)(&P[w][buf][l15][quad * 8]);        // ds_read_b128
        bf16x8 pa1 = *(const bf16x8*)(&P[w][buf][16 + l15][quad * 8]);
        o[0][0] = __builtin_amdgcn_mfma_f32_16x16x32_bf16(pa0, v0, o[0][0], 0, 0, 0);
        o[0][1] = __builtin_amdgcn_mfma_f32_16x16x32_bf16(pa0, v1, o[0][1], 0, 0, 0);
        o[1][0] = __builtin_amdgcn_mfma_f32_16x16x32_bf16(pa1, v0, o[1][0], 0, 0, 0);
        o[1][1] = __builtin_amdgcn_mfma_f32_16x16x32_bf16(pa1, v1, o[1][1], 0, 0, 0);

        k0 = k0n; k1 = k1n; v0 = v0n; v1 = v1n;
        c00 = n00; c10 = n10; c01 = n01; c11 = n11;
    }

    // row sums: i is lane-resident; partials differ only across quads
    psum0 += __shfl_xor(psum0, 16); psum0 += __shfl_xor(psum0, 32);
    psum1 += __shfl_xor(psum1, 16); psum1 += __shfl_xor(psum1, 32);
    if (quad == 0) { ssum[w][l15] = psum0; ssum[w][16 + l15] = psum1; }
    #pragma unroll
    for (int ih = 0; ih < 2; ++ih) {
        #pragma unroll
        for (int rr = 0; rr < 4; ++rr) {
            int il = ih * 16 + quad * 4 + rr;
            float inv = 1.f / ssum[w][il];
            size_t base = ((size_t)b * 640 + i0 + il) * 256 + h * 32;
            ctx[base + l15]      = (__bf16)(o[ih][0][rr] * inv);
            ctx[base + 16 + l15] = (__bf16)(o[ih][1][rr] * inv);
        }
    }
}

// -------- output projection, LDS-staged 64x256 tile, BK=32; transposed store ----------
__global__ __launch_bounds__(256, 2) void k_outproj(
    const __bf16* __restrict__ ctx,   // (b,640,256)
    const __bf16* __restrict__ WoT,   // (256,256)
    const int* __restrict__ flag,
    void* __restrict__ out)           // (b,256,625)
{
    __shared__ __align__(16) __bf16 As2[64][40];
    __shared__ __align__(16) __bf16 Bs2[256][40];
    int isbf = *flag;
    int b = blockIdx.y, pt = blockIdx.x;
    int p0 = pt * 64;
    int tid = threadIdx.x, w = tid >> 6, lane = tid & 63;
    int quad = lane >> 4, l15 = lane & 15;
    int srow = tid >> 2, scg = (tid & 3) * 8;
    const __bf16* ag = ctx + ((size_t)(b * 640 + p0 + srow) * 256) + scg;
    const __bf16* bg = WoT + (size_t)srow * 256 + scg;

    f32x4 acc[4][4] = {};
    for (int kk = 0; kk < 8; ++kk) {
        int c0 = kk * 32;
        bf16x8 a0 = *(const bf16x8*)(ag + c0);
        bf16x8 b0 = *(const bf16x8*)(bg + c0);
        bf16x8 b1 = *(const bf16x8*)(bg + 64 * 256 + c0);
        bf16x8 b2 = *(const bf16x8*)(bg + 128 * 256 + c0);
        bf16x8 b3 = *(const bf16x8*)(bg + 192 * 256 + c0);
        __syncthreads();
        *(bf16x8*)(&As2[srow][scg])       = a0;
        *(bf16x8*)(&Bs2[srow][scg])       = b0;
        *(bf16x8*)(&Bs2[64 + srow][scg])  = b1;
        *(bf16x8*)(&Bs2[128 + srow][scg]) = b2;
        *(bf16x8*)(&Bs2[192 + srow][scg]) = b3;
        __syncthreads();
        bf16x8 af[4], bfr[4];
        #pragma unroll
        for (int t = 0; t < 4; ++t) {
            af[t]  = *(const bf16x8*)(&As2[t * 16 + l15][quad * 8]);
            bfr[t] = *(const bf16x8*)(&Bs2[w * 64 + t * 16 + l15][quad * 8]);
        }
        #pragma unroll
        for (int i = 0; i < 4; ++i)
            #pragma unroll
            for (int j = 0; j < 4; ++j)
                acc[i][j] = __builtin_amdgcn_mfma_f32_16x16x32_bf16(af[i], bfr[j], acc[i][j], 0, 0, 0);
    }
    __bf16* outb = (__bf16*)out;
    float*  outf = (float*)out;
    #pragma unroll
    for (int i = 0; i < 4; ++i) {
        #pragma unroll
        for (int j = 0; j < 4; ++j) {
            int co = w * 64 + j * 16 + l15;
            #pragma unroll
            for (int rr = 0; rr < 4; ++rr) {
                int p = p0 + i * 16 + quad * 4 + rr;
                if (p < 625) {
                    size_t o = ((size_t)(b * 256) + co) * 625 + p;
                    if (isbf) outb[o] = (__bf16)acc[i][j][rr];
                    else      outf[o] = acc[i][j][rr];
                }
            }
        }
    }
}

extern "C" void kernel_launch(void* const* d_in, const int* in_sizes, int n_in,
                              void* d_out, int out_size, void* d_ws, size_t ws_size,
                              hipStream_t stream)
{
    const void* x    = d_in[0];
    const void* Wqkv = d_in[1];
    const void* Wout = d_in[2];
    const void* rel  = d_in[3];

    // ws layout (bf16 elems; 52.96 MB proven footprint). xT dead after k_qkv:
    // biasT and ctx alias its 10,485,760-elem region.
    __bf16* ws    = (__bf16*)d_ws;
    int*    flag  = (int*)d_ws;
    __bf16* xT    = ws + 64;
    __bf16* biasT = xT;                  // 3,276,800 elems
    __bf16* ctx   = xT + 3276800;        // 5,242,880 elems
    __bf16* Wt    = xT + 10485760;
    __bf16* WoT   = Wt + 196608;
    __bf16* Q     = WoT + 65536;
    __bf16* Km    = Q + 5242880;
    __bf16* Vt    = Km + 5242880;

    k_sniff<<<1, 64, 0, stream>>>((const unsigned short*)x, flag);
    k_transcvt<<<dim3(10, 4, 32), 256, 0, stream>>>(x, xT, flag, 256, 625, 640,
                                                    256 * 625, 640 * 256);
    k_wprep<<<dim3(16, 4), 256, 0, stream>>>(Wqkv, Wout, Wt, WoT, flag);
    k_qkv<<<dim3(6, 5, 32), 256, 0, stream>>>(xT, Wt, Q, Km, Vt);
    k_bias<<<640, 256, 0, stream>>>(rel, biasT, flag);   // after k_qkv (aliases xT)
    k_attn<<<dim3(256, 10), 128, 0, stream>>>(Q, Km, Vt, biasT, ctx);
    k_outproj<<<dim3(10, 32), 256, 0, stream>>>(ctx, WoT, flag, d_out);
}

// Round 7
// 180.929 us; speedup vs baseline: 1.2183x; 1.2183x over previous
//
#include <hip/hip_runtime.h>
#include <hip/hip_bf16.h>
#include <cstdint>

typedef __bf16 bf16x8 __attribute__((ext_vector_type(8)));
typedef __bf16 bf16x4 __attribute__((ext_vector_type(4)));
typedef float  f32x4  __attribute__((ext_vector_type(4)));

__device__ __forceinline__ int div25(int v) { return (v * 1311) >> 15; }  // exact for v <= 1310

#if __has_builtin(__builtin_amdgcn_exp2f)
__device__ __forceinline__ float fast_exp2(float x) { return __builtin_amdgcn_exp2f(x); }
#else
__device__ __forceinline__ float fast_exp2(float x) { return exp2f(x); }
#endif

// ---- inline dtype sniff: 16 uniform halfwords from one cache line; identical in all threads ----
__device__ __forceinline__ int sniff_isbf(const void* p)
{
    const unsigned short* x = (const unsigned short*)p;
    int cnt = 0;
    #pragma unroll
    for (int i = 0; i < 16; ++i) {
        int e = (x[2 * i] >> 7) & 0xFF;
        cnt += (e >= 90 && e <= 143) ? 1 : 0;
    }
    return cnt > 8;
}

// ---- transpose + convert x to bf16: (b,256,625) -> xT (b,640,256), pad rows zeroed ----
__global__ void k_transcvt(const void* __restrict__ src, __bf16* __restrict__ dst,
                           int R, int C, int Cpad, int src_bstride, int dst_bstride)
{
    __shared__ float tile[64][65];
    int isbf = sniff_isbf(src);
    int b  = blockIdx.z;
    int r0 = blockIdx.y * 64, c0 = blockIdx.x * 64;
    int tc = threadIdx.x & 63, tg = threadIdx.x >> 6;
    const unsigned short* sb = (const unsigned short*)src + (size_t)b * src_bstride;
    const float*          sf = (const float*)src          + (size_t)b * src_bstride;
    #pragma unroll
    for (int rr = 0; rr < 16; ++rr) {
        int r = r0 + tg * 16 + rr, c = c0 + tc;
        float v = 0.f;
        if (r < R && c < C) {
            if (isbf) v = __uint_as_float((unsigned int)sb[r * C + c] << 16);
            else      v = sf[r * C + c];
        }
        tile[tg * 16 + rr][tc] = v;
    }
    __syncthreads();
    __bf16* d = dst + (size_t)b * dst_bstride;
    #pragma unroll
    for (int rr = 0; rr < 16; ++rr) {
        int c = c0 + tg * 16 + rr, r = r0 + tc;
        if (c < Cpad && r < R) d[(size_t)c * R + r] = (__bf16)tile[tc][tg * 16 + rr];
    }
}

// ---- weight prep: transpose+cvt; fold qscale*log2e into q-columns of Wt ----
__global__ void k_wprep(const void* __restrict__ Wqkv, const void* __restrict__ Wout,
                        __bf16* __restrict__ Wt, __bf16* __restrict__ WoT)
{
    __shared__ float tile[64][65];
    int isbf = sniff_isbf(Wqkv);
    int isqkv = (blockIdx.x < 12);
    int bx = isqkv ? blockIdx.x : (blockIdx.x - 12);
    const void* src = isqkv ? Wqkv : Wout;
    __bf16* dst = isqkv ? Wt : WoT;
    int R = 256, C = isqkv ? 768 : 256;
    int r0 = blockIdx.y * 64, c0 = bx * 64;
    int tc = threadIdx.x & 63, tg = threadIdx.x >> 6;
    const unsigned short* sb = (const unsigned short*)src;
    const float*          sf = (const float*)src;
    #pragma unroll
    for (int rr = 0; rr < 16; ++rr) {
        int r = r0 + tg * 16 + rr, c = c0 + tc;
        float v;
        if (isbf) v = __uint_as_float((unsigned int)sb[r * C + c] << 16);
        else      v = sf[r * C + c];
        tile[tg * 16 + rr][tc] = v;
    }
    __syncthreads();
    const float qs = 0.25503494f;  // 32^-0.5 * log2(e)
    #pragma unroll
    for (int rr = 0; rr < 16; ++rr) {
        int c = c0 + tg * 16 + rr, r = r0 + tc;
        float v = tile[tc][tg * 16 + rr];
        if (isqkv && c < 256) v *= qs;
        dst[(size_t)c * R + r] = (__bf16)v;
    }
}

// ---- bias table in MFMA C-fragment order: biasC[((h*40+ig)*20+jc)*2+js][lane][4] bf16.
//      In-loop load becomes base+lane*8: fully coalesced (8 lines vs 64 for the old gather).
//      Values pre-multiplied by log2e; cols j>=625 = -43281 (exp2 -> 0). ----
__global__ void k_bias(const void* __restrict__ rel, __bf16* __restrict__ biasC)
{
    const float LOG2E = 1.4426950408889634f;
    int isbf = sniff_isbf(rel);
    int ig = blockIdx.x;      // i-group 0..39
    int h  = blockIdx.y;      // head 0..7
    for (int t0 = 0; t0 < 10; ++t0) {
        int t  = t0 * 256 + threadIdx.x;      // 0..2559
        int jc = t >> 7;                       // j-chunk 0..19
        int js = (t >> 6) & 1;                 // j-sub
        int ln = t & 63;
        int q = ln >> 4, l = ln & 15;
        int i = ig * 16 + l;
        int di = div25(i), ri = i - 25 * di;
        bf16x4 out;
        #pragma unroll
        for (int rr = 0; rr < 4; ++rr) {
            int j = jc * 32 + js * 16 + q * 4 + rr;
            float v;
            if (j >= 625) {
                v = -43281.f;
            } else {
                int dj = div25(j);
                int idx = (di - dj + 24) * 49 + ri - (j - 25 * dj) + 24;
                idx = min(max(idx, 0), 2400);
                float r;
                if (isbf) r = (float)((const __bf16*)rel)[idx * 8 + h];
                else      r = ((const float*)rel)[idx * 8 + h];
                v = r * LOG2E;
            }
            out[rr] = (__bf16)v;
        }
        *(bf16x4*)(biasC + ((size_t)(h * 40 + ig) * 20 + jc) * 512 + js * 256 + ln * 4) = out;
    }
}

// -------- QKV projection, LDS-staged 128x128 tile, BK=32, coalesced epilogue ----------
#define AS(r, c) pool[(size_t)(r) * 40 + (c)]
#define BS(r, c) pool[5120 + (size_t)(r) * 40 + (c)]
#define CS(r, c) pool[(size_t)(r) * 44 + (c)]
__global__ __launch_bounds__(256, 2) void k_qkv(
    const __bf16* __restrict__ xT,   // (b,640,256), pad rows zeroed
    const __bf16* __restrict__ Wt,   // (768,256)
    __bf16* __restrict__ Q,          // (b,8,640,32) scaled by 32^-.5*log2e
    __bf16* __restrict__ Km,         // (b,8,640,32)
    __bf16* __restrict__ Vt)         // (b,8,32,640)
{
    __shared__ __align__(16) __bf16 pool[10240];
    int b = blockIdx.z, pt = blockIdx.y, jt = blockIdx.x;
    int p0 = pt * 128, j0 = jt * 128;
    int tid = threadIdx.x;
    int w = tid >> 6, lane = tid & 63;
    int quad = lane >> 4, l15 = lane & 15;
    int wr = w >> 1, wc = w & 1;

    int srow = tid >> 2, scg = (tid & 3) * 8;
    const __bf16* ag  = xT + ((size_t)(b * 640 + p0 + srow) * 256) + scg;
    const __bf16* ag2 = ag + 64 * 256;
    const __bf16* bg  = Wt + ((size_t)(j0 + srow) * 256) + scg;
    const __bf16* bg2 = bg + 64 * 256;

    f32x4 acc[4][4] = {};
    for (int kk = 0; kk < 8; ++kk) {
        int c0 = kk * 32;
        bf16x8 a0 = *(const bf16x8*)(ag + c0);
        bf16x8 a1 = *(const bf16x8*)(ag2 + c0);
        bf16x8 b0 = *(const bf16x8*)(bg + c0);
        bf16x8 b1 = *(const bf16x8*)(bg2 + c0);
        __syncthreads();
        *(bf16x8*)(&AS(srow, scg))      = a0;
        *(bf16x8*)(&AS(64 + srow, scg)) = a1;
        *(bf16x8*)(&BS(srow, scg))      = b0;
        *(bf16x8*)(&BS(64 + srow, scg)) = b1;
        __syncthreads();
        bf16x8 af[4], bfr[4];
        #pragma unroll
        for (int t = 0; t < 4; ++t) {
            af[t]  = *(const bf16x8*)(&AS(wr * 64 + t * 16 + l15, quad * 8));
            bfr[t] = *(const bf16x8*)(&BS(wc * 64 + t * 16 + l15, quad * 8));
        }
        #pragma unroll
        for (int i = 0; i < 4; ++i)
            #pragma unroll
            for (int j = 0; j < 4; ++j)
                acc[i][j] = __builtin_amdgcn_mfma_f32_16x16x32_bf16(af[i], bfr[j], acc[i][j], 0, 0, 0);
    }

    if (jt < 4) {
        for (int r = 0; r < 4; ++r) {
            __syncthreads();
            if (wc == (r >> 1)) {
                #pragma unroll
                for (int i = 0; i < 4; ++i) {
                    #pragma unroll
                    for (int js = 0; js < 2; ++js) {
                        int jp = (r & 1) * 2 + js;
                        int col = js * 16 + l15;
                        int prow = wr * 64 + i * 16 + quad * 4;
                        #pragma unroll
                        for (int rr = 0; rr < 4; ++rr)
                            CS(prow + rr, col) = (__bf16)acc[i][jp][rr];
                    }
                }
            }
            __syncthreads();
            int jj = j0 + r * 32;
            __bf16* dst; int hh;
            if (jj < 256) { hh = jj >> 5; dst = Q; }
            else          { hh = (jj - 256) >> 5; dst = Km; }
            int p = tid >> 1, d0 = (tid & 1) * 16;
            size_t base = ((size_t)((b * 8 + hh) * 640) + p0 + p) * 32 + d0;
            #pragma unroll
            for (int k4 = 0; k4 < 4; ++k4) {
                bf16x4 v4 = *(const bf16x4*)(&CS(p, d0 + k4 * 4));
                *(bf16x4*)(dst + base + k4 * 4) = v4;
            }
        }
    } else {
        #pragma unroll
        for (int i = 0; i < 4; ++i) {
            #pragma unroll
            for (int j = 0; j < 4; ++j) {
                int jj = j0 + wc * 64 + j * 16 + l15 - 512;
                int h = jj >> 5, t = jj & 31;
                int p = p0 + wr * 64 + i * 16 + quad * 4;
                bf16x4 vv;
                #pragma unroll
                for (int rr = 0; rr < 4; ++rr) vv[rr] = (__bf16)acc[i][j][rr];
                *(bf16x4*)(Vt + ((size_t)((b * 8 + h) * 32) + t) * 640 + p) = vv;
            }
        }
    }
}

// -------- fused attention v6: 64 i/wave, coalesced C-order bias, pipelined P bounce ----------
// grid(x=bh, y=5): XCD-local (%8 -> head-per-XCD). Wave-private i-tile, zero barriers.
__global__ __launch_bounds__(128, 3) void k_attn(
    const __bf16* __restrict__ Q,
    const __bf16* __restrict__ Km,
    const __bf16* __restrict__ Vt,
    const __bf16* __restrict__ biasC,  // C-fragment-ordered, *log2e
    __bf16* __restrict__ ctx)          // (b,640,256), channel = h*32+dh
{
    __shared__ __align__(16) __bf16 P[2][2][64][40];   // [wave][buf][i][j] 20.5 KB
    __shared__ float ssum[2][64];
    int bh = blockIdx.x, b = bh >> 3, h = bh & 7;
    int tid = threadIdx.x, w = tid >> 6, lane = tid & 63;
    int quad = lane >> 4, l15 = lane & 15;
    int i0 = (blockIdx.y * 2 + w) * 64;    // wave-private 64-row i-tile

    bf16x8 qa[4];
    #pragma unroll
    for (int m = 0; m < 4; ++m)
        qa[m] = *(const bf16x8*)(Q + ((size_t)bh * 640 + i0 + 16 * m + l15) * 32 + quad * 8);
    const __bf16* kbase = Km + (size_t)bh * 640 * 32 + quad * 8;
    const __bf16* vbase = Vt + ((size_t)bh * 32 + l15) * 640 + quad * 8;
    const __bf16* bcb   = biasC + (size_t)(h * 40 + (i0 >> 4)) * 10240 + lane * 4;

    f32x4 o[4][2] = {};
    float psum[4] = {0.f, 0.f, 0.f, 0.f};

    // preload chunk 0 K + bias
    bf16x8 k0 = *(const bf16x8*)(kbase + (size_t)l15 * 32);
    bf16x8 k1 = *(const bf16x8*)(kbase + (size_t)(16 + l15) * 32);
    bf16x4 bc[4][2];
    #pragma unroll
    for (int m = 0; m < 4; ++m) {
        bc[m][0] = *(const bf16x4*)(bcb + m * 10240);
        bc[m][1] = *(const bf16x4*)(bcb + m * 10240 + 256);
    }
    bf16x8 vC0 = {}, vC1 = {};

    for (int c = 0; c < 20; ++c) {
        int buf = c & 1;
        // PV for chunk c-1: reads prev buf (written last iteration by this wave)
        if (c > 0) {
            #pragma unroll
            for (int m = 0; m < 4; ++m) {
                bf16x8 pa = *(const bf16x8*)(&P[w][buf ^ 1][16 * m + l15][quad * 8]);
                o[m][0] = __builtin_amdgcn_mfma_f32_16x16x32_bf16(pa, vC0, o[m][0], 0, 0, 0);
                o[m][1] = __builtin_amdgcn_mfma_f32_16x16x32_bf16(pa, vC1, o[m][1], 0, 0, 0);
            }
        }
        // loads: K/bias for chunk c+1, V for chunk c (consumed by PV next iteration)
        int cn = min(c + 1, 19);
        bf16x8 k0n = *(const bf16x8*)(kbase + (size_t)(cn * 32 + l15) * 32);
        bf16x8 k1n = *(const bf16x8*)(kbase + (size_t)(cn * 32 + 16 + l15) * 32);
        bf16x8 vN0 = *(const bf16x8*)(vbase + c * 32);
        bf16x8 vN1 = *(const bf16x8*)(vbase + (size_t)16 * 640 + c * 32);
        bf16x4 bn[4][2];
        #pragma unroll
        for (int m = 0; m < 4; ++m) {
            bn[m][0] = *(const bf16x4*)(bcb + m * 10240 + cn * 512);
            bn[m][1] = *(const bf16x4*)(bcb + m * 10240 + cn * 512 + 256);
        }
        // S phase for chunk c (bias as C-seed; exp2; write P)
        #pragma unroll
        for (int m = 0; m < 4; ++m) {
            f32x4 f0, f1;
            #pragma unroll
            for (int rr = 0; rr < 4; ++rr) { f0[rr] = (float)bc[m][0][rr]; f1[rr] = (float)bc[m][1][rr]; }
            f32x4 s0 = __builtin_amdgcn_mfma_f32_16x16x32_bf16(k0, qa[m], f0, 0, 0, 0);
            f32x4 s1 = __builtin_amdgcn_mfma_f32_16x16x32_bf16(k1, qa[m], f1, 0, 0, 0);
            bf16x4 p0, p1;
            #pragma unroll
            for (int rr = 0; rr < 4; ++rr) {
                float e0 = fast_exp2(s0[rr]); psum[m] += e0; p0[rr] = (__bf16)e0;
                float e1 = fast_exp2(s1[rr]); psum[m] += e1; p1[rr] = (__bf16)e1;
            }
            *(bf16x4*)(&P[w][buf][16 * m + l15][quad * 4])      = p0;   // ds_write_b64
            *(bf16x4*)(&P[w][buf][16 * m + l15][16 + quad * 4]) = p1;
        }
        k0 = k0n; k1 = k1n; vC0 = vN0; vC1 = vN1;
        #pragma unroll
        for (int m = 0; m < 4; ++m) { bc[m][0] = bn[m][0]; bc[m][1] = bn[m][1]; }
    }
    // final PV (chunk 19, buf 1)
    #pragma unroll
    for (int m = 0; m < 4; ++m) {
        bf16x8 pa = *(const bf16x8*)(&P[w][1][16 * m + l15][quad * 8]);
        o[m][0] = __builtin_amdgcn_mfma_f32_16x16x32_bf16(pa, vC0, o[m][0], 0, 0, 0);
        o[m][1] = __builtin_amdgcn_mfma_f32_16x16x32_bf16(pa, vC1, o[m][1], 0, 0, 0);
    }

    // row sums: i lane-resident; reduce over quads
    #pragma unroll
    for (int m = 0; m < 4; ++m) {
        psum[m] += __shfl_xor(psum[m], 16);
        psum[m] += __shfl_xor(psum[m], 32);
    }
    if (quad == 0)
        #pragma unroll
        for (int m = 0; m < 4; ++m) ssum[w][16 * m + l15] = psum[m];
    // wave-internal LDS round-trip (in-order per wave; no barrier needed)
    #pragma unroll
    for (int m = 0; m < 4; ++m) {
        #pragma unroll
        for (int rr = 0; rr < 4; ++rr) {
            int il = 16 * m + quad * 4 + rr;
            float inv = 1.f / ssum[w][il];
            size_t base = ((size_t)b * 640 + i0 + il) * 256 + h * 32;
            ctx[base + l15]      = (__bf16)(o[m][0][rr] * inv);
            ctx[base + 16 + l15] = (__bf16)(o[m][1][rr] * inv);
        }
    }
}

// -------- output projection, LDS-staged 64x256 tile, BK=32; transposed store ----------
__global__ __launch_bounds__(256, 2) void k_outproj(
    const __bf16* __restrict__ ctx,   // (b,640,256)
    const __bf16* __restrict__ WoT,   // (256,256)
    const void* __restrict__ xorig,   // for dtype sniff only
    void* __restrict__ out)           // (b,256,625)
{
    __shared__ __align__(16) __bf16 As2[64][40];
    __shared__ __align__(16) __bf16 Bs2[256][40];
    int isbf = sniff_isbf(xorig);
    int b = blockIdx.y, pt = blockIdx.x;
    int p0 = pt * 64;
    int tid = threadIdx.x, w = tid >> 6, lane = tid & 63;
    int quad = lane >> 4, l15 = lane & 15;
    int srow = tid >> 2, scg = (tid & 3) * 8;
    const __bf16* ag = ctx + ((size_t)(b * 640 + p0 + srow) * 256) + scg;
    const __bf16* bg = WoT + (size_t)srow * 256 + scg;

    f32x4 acc[4][4] = {};
    for (int kk = 0; kk < 8; ++kk) {
        int c0 = kk * 32;
        bf16x8 a0 = *(const bf16x8*)(ag + c0);
        bf16x8 b0 = *(const bf16x8*)(bg + c0);
        bf16x8 b1 = *(const bf16x8*)(bg + 64 * 256 + c0);
        bf16x8 b2 = *(const bf16x8*)(bg + 128 * 256 + c0);
        bf16x8 b3 = *(const bf16x8*)(bg + 192 * 256 + c0);
        __syncthreads();
        *(bf16x8*)(&As2[srow][scg])       = a0;
        *(bf16x8*)(&Bs2[srow][scg])       = b0;
        *(bf16x8*)(&Bs2[64 + srow][scg])  = b1;
        *(bf16x8*)(&Bs2[128 + srow][scg]) = b2;
        *(bf16x8*)(&Bs2[192 + srow][scg]) = b3;
        __syncthreads();
        bf16x8 af[4], bfr[4];
        #pragma unroll
        for (int t = 0; t < 4; ++t) {
            af[t]  = *(const bf16x8*)(&As2[t * 16 + l15][quad * 8]);
            bfr[t] = *(const bf16x8*)(&Bs2[w * 64 + t * 16 + l15][quad * 8]);
        }
        #pragma unroll
        for (int i = 0; i < 4; ++i)
            #pragma unroll
            for (int j = 0; j < 4; ++j)
                acc[i][j] = __builtin_amdgcn_mfma_f32_16x16x32_bf16(af[i], bfr[j], acc[i][j], 0, 0, 0);
    }
    __bf16* outb = (__bf16*)out;
    float*  outf = (float*)out;
    #pragma unroll
    for (int i = 0; i < 4; ++i) {
        #pragma unroll
        for (int j = 0; j < 4; ++j) {
            int co = w * 64 + j * 16 + l15;
            #pragma unroll
            for (int rr = 0; rr < 4; ++rr) {
                int p = p0 + i * 16 + quad * 4 + rr;
                if (p < 625) {
                    size_t o = ((size_t)(b * 256) + co) * 625 + p;
                    if (isbf) outb[o] = (__bf16)acc[i][j][rr];
                    else      outf[o] = acc[i][j][rr];
                }
            }
        }
    }
}

extern "C" void kernel_launch(void* const* d_in, const int* in_sizes, int n_in,
                              void* d_out, int out_size, void* d_ws, size_t ws_size,
                              hipStream_t stream)
{
    const void* x    = d_in[0];
    const void* Wqkv = d_in[1];
    const void* Wout = d_in[2];
    const void* rel  = d_in[3];

    // ws layout (bf16 elems; 52.96 MB proven footprint). xT dead after k_qkv:
    // biasC and ctx alias its 10,485,760-elem region.
    __bf16* ws    = (__bf16*)d_ws;
    __bf16* xT    = ws + 64;
    __bf16* biasC = xT;                  // 3,276,800 elems (C-fragment-ordered table)
    __bf16* ctx   = xT + 3276800;        // 5,242,880 elems
    __bf16* Wt    = xT + 10485760;
    __bf16* WoT   = Wt + 196608;
    __bf16* Q     = WoT + 65536;
    __bf16* Km    = Q + 5242880;
    __bf16* Vt    = Km + 5242880;

    k_transcvt<<<dim3(10, 4, 32), 256, 0, stream>>>(x, xT, 256, 625, 640,
                                                    256 * 625, 640 * 256);
    k_wprep<<<dim3(16, 4), 256, 0, stream>>>(Wqkv, Wout, Wt, WoT);
    k_qkv<<<dim3(6, 5, 32), 256, 0, stream>>>(xT, Wt, Q, Km, Vt);
    k_bias<<<dim3(40, 8), 256, 0, stream>>>(rel, biasC);   // after k_qkv (aliases xT)
    k_attn<<<dim3(256, 5), 128, 0, stream>>>(Q, Km, Vt, biasC, ctx);
    k_outproj<<<dim3(10, 32), 256, 0, stream>>>(ctx, WoT, x, d_out);
}

// Round 8
// 161.012 us; speedup vs baseline: 1.3690x; 1.1237x over previous
//
#include <hip/hip_runtime.h>
#include <hip/hip_bf16.h>
#include <cstdint>

typedef __bf16 bf16x8 __attribute__((ext_vector_type(8)));
typedef __bf16 bf16x4 __attribute__((ext_vector_type(4)));
typedef float  f32x4  __attribute__((ext_vector_type(4)));

__device__ __forceinline__ int div25(int v) { return (v * 1311) >> 15; }  // exact for v <= 1310

#if __has_builtin(__builtin_amdgcn_exp2f)
__device__ __forceinline__ float fast_exp2(float x) { return __builtin_amdgcn_exp2f(x); }
#else
__device__ __forceinline__ float fast_exp2(float x) { return exp2f(x); }
#endif

// ---- inline dtype sniff: 16 uniform halfwords from one cache line ----
__device__ __forceinline__ int sniff_isbf(const void* p)
{
    const unsigned short* x = (const unsigned short*)p;
    int cnt = 0;
    #pragma unroll
    for (int i = 0; i < 16; ++i) {
        int e = (x[2 * i] >> 7) & 0xFF;
        cnt += (e >= 90 && e <= 143) ? 1 : 0;
    }
    return cnt > 8;
}

// ================= fused preprocessing: one launch, 3 independent jobs =================
// blocks [0,1280): x transpose+cvt  (b,256,625)->xT (b,640,256), pad rows zeroed
// blocks [1280,1344): weight prep   Wqkv/Wout -> Wt/WoT (transposed, qscale*log2e folded)
// blocks [1344,1664): bias table in MFMA C-fragment order, *log2e
__global__ __launch_bounds__(256) void k_pre(
    const void* __restrict__ x, const void* __restrict__ Wqkv,
    const void* __restrict__ Wout, const void* __restrict__ rel,
    __bf16* __restrict__ xT, __bf16* __restrict__ Wt, __bf16* __restrict__ WoT,
    __bf16* __restrict__ biasC)
{
    __shared__ float tile[64][65];
    int bid = blockIdx.x;
    if (bid < 1280) {
        // ---- x transpose ----
        int isbf = sniff_isbf(x);
        int b = bid / 40, rem = bid % 40;
        int c0 = (rem % 10) * 64, r0 = (rem / 10) * 64;
        const int R = 256, C = 625, Cpad = 640;
        int tc = threadIdx.x & 63, tg = threadIdx.x >> 6;
        const unsigned short* sb = (const unsigned short*)x + (size_t)b * (256 * 625);
        const float*          sf = (const float*)x          + (size_t)b * (256 * 625);
        #pragma unroll
        for (int rr = 0; rr < 16; ++rr) {
            int r = r0 + tg * 16 + rr, c = c0 + tc;
            float v = 0.f;
            if (r < R && c < C) {
                if (isbf) v = __uint_as_float((unsigned int)sb[r * C + c] << 16);
                else      v = sf[r * C + c];
            }
            tile[tg * 16 + rr][tc] = v;
        }
        __syncthreads();
        __bf16* d = xT + (size_t)b * (640 * 256);
        #pragma unroll
        for (int rr = 0; rr < 16; ++rr) {
            int c = c0 + tg * 16 + rr, r = r0 + tc;
            if (c < Cpad && r < R) d[(size_t)c * R + r] = (__bf16)tile[tc][tg * 16 + rr];
        }
    } else if (bid < 1344) {
        // ---- weight prep ----
        int q = bid - 1280;
        int bx = q % 16, by = q / 16;
        int isbf = sniff_isbf(Wqkv);
        int isqkv = (bx < 12);
        int bxx = isqkv ? bx : (bx - 12);
        const void* src = isqkv ? Wqkv : Wout;
        __bf16* dst = isqkv ? Wt : WoT;
        int R = 256, C = isqkv ? 768 : 256;
        int r0 = by * 64, c0 = bxx * 64;
        int tc = threadIdx.x & 63, tg = threadIdx.x >> 6;
        const unsigned short* sb = (const unsigned short*)src;
        const float*          sf = (const float*)src;
        #pragma unroll
        for (int rr = 0; rr < 16; ++rr) {
            int r = r0 + tg * 16 + rr, c = c0 + tc;
            float v;
            if (isbf) v = __uint_as_float((unsigned int)sb[r * C + c] << 16);
            else      v = sf[r * C + c];
            tile[tg * 16 + rr][tc] = v;
        }
        __syncthreads();
        const float qs = 0.25503494f;  // 32^-0.5 * log2(e)
        #pragma unroll
        for (int rr = 0; rr < 16; ++rr) {
            int c = c0 + tg * 16 + rr, r = r0 + tc;
            float v = tile[tc][tg * 16 + rr];
            if (isqkv && c < 256) v *= qs;
            dst[(size_t)c * R + r] = (__bf16)v;
        }
    } else {
        // ---- bias table: biasC[((h*40+ig)*20+jc)*512 + js*256 + lane*4 + rr] ----
        const float LOG2E = 1.4426950408889634f;
        int isbf = sniff_isbf(rel);
        int q = bid - 1344;
        int ig = q % 40, h = q / 40;
        for (int t0 = 0; t0 < 10; ++t0) {
            int t  = t0 * 256 + threadIdx.x;
            int jc = t >> 7;
            int js = (t >> 6) & 1;
            int ln = t & 63;
            int qd = ln >> 4, l = ln & 15;
            int i = ig * 16 + l;
            int di = div25(i), ri = i - 25 * di;
            bf16x4 out;
            #pragma unroll
            for (int rr = 0; rr < 4; ++rr) {
                int j = jc * 32 + js * 16 + qd * 4 + rr;
                float v;
                if (j >= 625) {
                    v = -43281.f;
                } else {
                    int dj = div25(j);
                    int idx = (di - dj + 24) * 49 + ri - (j - 25 * dj) + 24;
                    idx = min(max(idx, 0), 2400);
                    float r;
                    if (isbf) r = (float)((const __bf16*)rel)[idx * 8 + h];
                    else      r = ((const float*)rel)[idx * 8 + h];
                    v = r * LOG2E;
                }
                out[rr] = (__bf16)v;
            }
            *(bf16x4*)(biasC + ((size_t)(h * 40 + ig) * 20 + jc) * 512 + js * 256 + ln * 4) = out;
        }
    }
}

// -------- QKV projection, LDS-staged 128x128 tile, BK=32, coalesced epilogue ----------
#define AS(r, c) pool[(size_t)(r) * 40 + (c)]
#define BS(r, c) pool[5120 + (size_t)(r) * 40 + (c)]
#define CS(r, c) pool[(size_t)(r) * 44 + (c)]
__global__ __launch_bounds__(256, 2) void k_qkv(
    const __bf16* __restrict__ xT,   // (b,640,256), pad rows zeroed
    const __bf16* __restrict__ Wt,   // (768,256)
    __bf16* __restrict__ Q,          // (b,8,640,32) scaled by 32^-.5*log2e
    __bf16* __restrict__ Km,         // (b,8,640,32)
    __bf16* __restrict__ Vt)         // (b,8,32,640)
{
    __shared__ __align__(16) __bf16 pool[10240];
    int b = blockIdx.z, pt = blockIdx.y, jt = blockIdx.x;
    int p0 = pt * 128, j0 = jt * 128;
    int tid = threadIdx.x;
    int w = tid >> 6, lane = tid & 63;
    int quad = lane >> 4, l15 = lane & 15;
    int wr = w >> 1, wc = w & 1;

    int srow = tid >> 2, scg = (tid & 3) * 8;
    const __bf16* ag  = xT + ((size_t)(b * 640 + p0 + srow) * 256) + scg;
    const __bf16* ag2 = ag + 64 * 256;
    const __bf16* bg  = Wt + ((size_t)(j0 + srow) * 256) + scg;
    const __bf16* bg2 = bg + 64 * 256;

    f32x4 acc[4][4] = {};
    for (int kk = 0; kk < 8; ++kk) {
        int c0 = kk * 32;
        bf16x8 a0 = *(const bf16x8*)(ag + c0);
        bf16x8 a1 = *(const bf16x8*)(ag2 + c0);
        bf16x8 b0 = *(const bf16x8*)(bg + c0);
        bf16x8 b1 = *(const bf16x8*)(bg2 + c0);
        __syncthreads();
        *(bf16x8*)(&AS(srow, scg))      = a0;
        *(bf16x8*)(&AS(64 + srow, scg)) = a1;
        *(bf16x8*)(&BS(srow, scg))      = b0;
        *(bf16x8*)(&BS(64 + srow, scg)) = b1;
        __syncthreads();
        bf16x8 af[4], bfr[4];
        #pragma unroll
        for (int t = 0; t < 4; ++t) {
            af[t]  = *(const bf16x8*)(&AS(wr * 64 + t * 16 + l15, quad * 8));
            bfr[t] = *(const bf16x8*)(&BS(wc * 64 + t * 16 + l15, quad * 8));
        }
        #pragma unroll
        for (int i = 0; i < 4; ++i)
            #pragma unroll
            for (int j = 0; j < 4; ++j)
                acc[i][j] = __builtin_amdgcn_mfma_f32_16x16x32_bf16(af[i], bfr[j], acc[i][j], 0, 0, 0);
    }

    if (jt < 4) {
        for (int r = 0; r < 4; ++r) {
            __syncthreads();
            if (wc == (r >> 1)) {
                #pragma unroll
                for (int i = 0; i < 4; ++i) {
                    #pragma unroll
                    for (int js = 0; js < 2; ++js) {
                        int jp = (r & 1) * 2 + js;
                        int col = js * 16 + l15;
                        int prow = wr * 64 + i * 16 + quad * 4;
                        #pragma unroll
                        for (int rr = 0; rr < 4; ++rr)
                            CS(prow + rr, col) = (__bf16)acc[i][jp][rr];
                    }
                }
            }
            __syncthreads();
            int jj = j0 + r * 32;
            __bf16* dst; int hh;
            if (jj < 256) { hh = jj >> 5; dst = Q; }
            else          { hh = (jj - 256) >> 5; dst = Km; }
            int p = tid >> 1, d0 = (tid & 1) * 16;
            size_t base = ((size_t)((b * 8 + hh) * 640) + p0 + p) * 32 + d0;
            #pragma unroll
            for (int k4 = 0; k4 < 4; ++k4) {
                bf16x4 v4 = *(const bf16x4*)(&CS(p, d0 + k4 * 4));
                *(bf16x4*)(dst + base + k4 * 4) = v4;
            }
        }
    } else {
        #pragma unroll
        for (int i = 0; i < 4; ++i) {
            #pragma unroll
            for (int j = 0; j < 4; ++j) {
                int jj = j0 + wc * 64 + j * 16 + l15 - 512;
                int h = jj >> 5, t = jj & 31;
                int p = p0 + wr * 64 + i * 16 + quad * 4;
                bf16x4 vv;
                #pragma unroll
                for (int rr = 0; rr < 4; ++rr) vv[rr] = (__bf16)acc[i][j][rr];
                *(bf16x4*)(Vt + ((size_t)((b * 8 + h) * 32) + t) * 640 + p) = vv;
            }
        }
    }
}

// -------- fused attention v7: reordered chain S -> loads -> PV(c-1) -> write P(c) ----------
// grid(x=bh, y=5): XCD-local (%8 -> head-per-XCD). Wave-private 64-row i-tile, zero barriers.
__global__ __launch_bounds__(128, 3) void k_attn(
    const __bf16* __restrict__ Q,
    const __bf16* __restrict__ Km,
    const __bf16* __restrict__ Vt,
    const __bf16* __restrict__ biasC,  // C-fragment-ordered, *log2e
    __bf16* __restrict__ ctx)          // (b,640,256), channel = h*32+dh
{
    __shared__ __align__(16) __bf16 P[2][2][64][40];   // [wave][buf][i][j] 20.5 KB
    __shared__ float ssum[2][64];
    int bh = blockIdx.x, b = bh >> 3, h = bh & 7;
    int tid = threadIdx.x, w = tid >> 6, lane = tid & 63;
    int quad = lane >> 4, l15 = lane & 15;
    int i0 = (blockIdx.y * 2 + w) * 64;

    bf16x8 qa[4];
    #pragma unroll
    for (int m = 0; m < 4; ++m)
        qa[m] = *(const bf16x8*)(Q + ((size_t)bh * 640 + i0 + 16 * m + l15) * 32 + quad * 8);
    const __bf16* kbase = Km + (size_t)bh * 640 * 32 + quad * 8;
    const __bf16* vbase = Vt + ((size_t)bh * 32 + l15) * 640 + quad * 8;
    const __bf16* bcb   = biasC + (size_t)(h * 40 + (i0 >> 4)) * 10240 + lane * 4;

    f32x4 o[4][2] = {};
    float psum[4] = {0.f, 0.f, 0.f, 0.f};

    // preload chunk 0 K + bias
    bf16x8 k0 = *(const bf16x8*)(kbase + (size_t)l15 * 32);
    bf16x8 k1 = *(const bf16x8*)(kbase + (size_t)(16 + l15) * 32);
    bf16x4 bc[4][2];
    #pragma unroll
    for (int m = 0; m < 4; ++m) {
        bc[m][0] = *(const bf16x4*)(bcb + m * 10240);
        bc[m][1] = *(const bf16x4*)(bcb + m * 10240 + 256);
    }
    bf16x8 vC0 = {}, vC1 = {};

    for (int c = 0; c < 20; ++c) {
        int buf = c & 1;
        // ---- S-MFMAs for chunk c (K/bias already resident) ----
        f32x4 s[4][2];
        #pragma unroll
        for (int m = 0; m < 4; ++m) {
            f32x4 f0, f1;
            #pragma unroll
            for (int rr = 0; rr < 4; ++rr) { f0[rr] = (float)bc[m][0][rr]; f1[rr] = (float)bc[m][1][rr]; }
            s[m][0] = __builtin_amdgcn_mfma_f32_16x16x32_bf16(k0, qa[m], f0, 0, 0, 0);
            s[m][1] = __builtin_amdgcn_mfma_f32_16x16x32_bf16(k1, qa[m], f1, 0, 0, 0);
        }
        // ---- issue prefetches: K/bias for c+1, V for c ----
        int cn = min(c + 1, 19);
        bf16x8 k0n = *(const bf16x8*)(kbase + (size_t)(cn * 32 + l15) * 32);
        bf16x8 k1n = *(const bf16x8*)(kbase + (size_t)(cn * 32 + 16 + l15) * 32);
        bf16x8 vN0 = *(const bf16x8*)(vbase + c * 32);
        bf16x8 vN1 = *(const bf16x8*)(vbase + (size_t)16 * 640 + c * 32);
        bf16x4 bn[4][2];
        #pragma unroll
        for (int m = 0; m < 4; ++m) {
            bn[m][0] = *(const bf16x4*)(bcb + m * 10240 + cn * 512);
            bn[m][1] = *(const bf16x4*)(bcb + m * 10240 + cn * 512 + 256);
        }
        // ---- exp/pack for chunk c (held in regs) ----
        bf16x4 pk[4][2];
        #pragma unroll
        for (int m = 0; m < 4; ++m) {
            #pragma unroll
            for (int rr = 0; rr < 4; ++rr) {
                float e0 = fast_exp2(s[m][0][rr]); psum[m] += e0; pk[m][0][rr] = (__bf16)e0;
                float e1 = fast_exp2(s[m][1][rr]); psum[m] += e1; pk[m][1][rr] = (__bf16)e1;
            }
        }
        // ---- PV for chunk c-1 (P written one full iteration ago) ----
        if (c > 0) {
            #pragma unroll
            for (int m = 0; m < 4; ++m) {
                bf16x8 pa = *(const bf16x8*)(&P[w][buf ^ 1][16 * m + l15][quad * 8]);
                o[m][0] = __builtin_amdgcn_mfma_f32_16x16x32_bf16(pa, vC0, o[m][0], 0, 0, 0);
                o[m][1] = __builtin_amdgcn_mfma_f32_16x16x32_bf16(pa, vC1, o[m][1], 0, 0, 0);
            }
        }
        // ---- write P(c) (read next iteration) ----
        #pragma unroll
        for (int m = 0; m < 4; ++m) {
            *(bf16x4*)(&P[w][buf][16 * m + l15][quad * 4])      = pk[m][0];
            *(bf16x4*)(&P[w][buf][16 * m + l15][16 + quad * 4]) = pk[m][1];
        }
        k0 = k0n; k1 = k1n; vC0 = vN0; vC1 = vN1;
        #pragma unroll
        for (int m = 0; m < 4; ++m) { bc[m][0] = bn[m][0]; bc[m][1] = bn[m][1]; }
    }
    // final PV (chunk 19, buf 1)
    #pragma unroll
    for (int m = 0; m < 4; ++m) {
        bf16x8 pa = *(const bf16x8*)(&P[w][1][16 * m + l15][quad * 8]);
        o[m][0] = __builtin_amdgcn_mfma_f32_16x16x32_bf16(pa, vC0, o[m][0], 0, 0, 0);
        o[m][1] = __builtin_amdgcn_mfma_f32_16x16x32_bf16(pa, vC1, o[m][1], 0, 0, 0);
    }

    // row sums: i lane-resident; reduce over quads
    #pragma unroll
    for (int m = 0; m < 4; ++m) {
        psum[m] += __shfl_xor(psum[m], 16);
        psum[m] += __shfl_xor(psum[m], 32);
    }
    if (quad == 0)
        #pragma unroll
        for (int m = 0; m < 4; ++m) ssum[w][16 * m + l15] = psum[m];
    #pragma unroll
    for (int m = 0; m < 4; ++m) {
        #pragma unroll
        for (int rr = 0; rr < 4; ++rr) {
            int il = 16 * m + quad * 4 + rr;
            float inv = 1.f / ssum[w][il];
            size_t base = ((size_t)b * 640 + i0 + il) * 256 + h * 32;
            ctx[base + l15]      = (__bf16)(o[m][0][rr] * inv);
            ctx[base + 16 + l15] = (__bf16)(o[m][1][rr] * inv);
        }
    }
}

// -------- output projection, LDS-staged 64x256 tile, BK=32; transposed store ----------
__global__ __launch_bounds__(256, 2) void k_outproj(
    const __bf16* __restrict__ ctx,   // (b,640,256)
    const __bf16* __restrict__ WoT,   // (256,256)
    const void* __restrict__ xorig,   // dtype sniff only
    void* __restrict__ out)           // (b,256,625)
{
    __shared__ __align__(16) __bf16 As2[64][40];
    __shared__ __align__(16) __bf16 Bs2[256][40];
    int isbf = sniff_isbf(xorig);
    int b = blockIdx.y, pt = blockIdx.x;
    int p0 = pt * 64;
    int tid = threadIdx.x, w = tid >> 6, lane = tid & 63;
    int quad = lane >> 4, l15 = lane & 15;
    int srow = tid >> 2, scg = (tid & 3) * 8;
    const __bf16* ag = ctx + ((size_t)(b * 640 + p0 + srow) * 256) + scg;
    const __bf16* bg = WoT + (size_t)srow * 256 + scg;

    f32x4 acc[4][4] = {};
    for (int kk = 0; kk < 8; ++kk) {
        int c0 = kk * 32;
        bf16x8 a0 = *(const bf16x8*)(ag + c0);
        bf16x8 b0 = *(const bf16x8*)(bg + c0);
        bf16x8 b1 = *(const bf16x8*)(bg + 64 * 256 + c0);
        bf16x8 b2 = *(const bf16x8*)(bg + 128 * 256 + c0);
        bf16x8 b3 = *(const bf16x8*)(bg + 192 * 256 + c0);
        __syncthreads();
        *(bf16x8*)(&As2[srow][scg])       = a0;
        *(bf16x8*)(&Bs2[srow][scg])       = b0;
        *(bf16x8*)(&Bs2[64 + srow][scg])  = b1;
        *(bf16x8*)(&Bs2[128 + srow][scg]) = b2;
        *(bf16x8*)(&Bs2[192 + srow][scg]) = b3;
        __syncthreads();
        bf16x8 af[4], bfr[4];
        #pragma unroll
        for (int t = 0; t < 4; ++t) {
            af[t]  = *(const bf16x8*)(&As2[t * 16 + l15][quad * 8]);
            bfr[t] = *(const bf16x8*)(&Bs2[w * 64 + t * 16 + l15][quad * 8]);
        }
        #pragma unroll
        for (int i = 0; i < 4; ++i)
            #pragma unroll
            for (int j = 0; j < 4; ++j)
                acc[i][j] = __builtin_amdgcn_mfma_f32_16x16x32_bf16(af[i], bfr[j], acc[i][j], 0, 0, 0);
    }
    __bf16* outb = (__bf16*)out;
    float*  outf = (float*)out;
    #pragma unroll
    for (int i = 0; i < 4; ++i) {
        #pragma unroll
        for (int j = 0; j < 4; ++j) {
            int co = w * 64 + j * 16 + l15;
            #pragma unroll
            for (int rr = 0; rr < 4; ++rr) {
                int p = p0 + i * 16 + quad * 4 + rr;
                if (p < 625) {
                    size_t o = ((size_t)(b * 256) + co) * 625 + p;
                    if (isbf) outb[o] = (__bf16)acc[i][j][rr];
                    else      outf[o] = acc[i][j][rr];
                }
            }
        }
    }
}

extern "C" void kernel_launch(void* const* d_in, const int* in_sizes, int n_in,
                              void* d_out, int out_size, void* d_ws, size_t ws_size,
                              hipStream_t stream)
{
    const void* x    = d_in[0];
    const void* Wqkv = d_in[1];
    const void* Wout = d_in[2];
    const void* rel  = d_in[3];

    // ws layout, NO aliasing (ws_size is 256 MiB per the harness fill; we use ~70 MB).
    __bf16* ws    = (__bf16*)d_ws;
    __bf16* xT    = ws;                      // 10,485,760 elems
    __bf16* Wt    = xT + 10485760;           //    196,608
    __bf16* WoT   = Wt + 196608;             //     65,536
    __bf16* Q     = WoT + 65536;             //  5,242,880
    __bf16* Km    = Q + 5242880;             //  5,242,880
    __bf16* Vt    = Km + 5242880;            //  5,242,880
    __bf16* biasC = Vt + 5242880;            //  3,276,800
    __bf16* ctx   = biasC + 3276800;         //  5,242,880   (total ~70 MB)

    k_pre<<<1664, 256, 0, stream>>>(x, Wqkv, Wout, rel, xT, Wt, WoT, biasC);
    k_qkv<<<dim3(6, 5, 32), 256, 0, stream>>>(xT, Wt, Q, Km, Vt);
    k_attn<<<dim3(256, 5), 128, 0, stream>>>(Q, Km, Vt, biasC, ctx);
    k_outproj<<<dim3(10, 32), 256, 0, stream>>>(ctx, WoT, x, d_out);
}